// Round 4
// baseline (344.639 us; speedup 1.0000x reference)
//
#include <hip/hip_runtime.h>
#include <hip/hip_bf16.h>

typedef __bf16 bf16x8 __attribute__((ext_vector_type(8)));
typedef float floatx4 __attribute__((ext_vector_type(4)));

#define MFMA16(a, b, c) __builtin_amdgcn_mfma_f32_16x16x32_bf16(a, b, c, 0, 0, 0)

constexpr int D = 1024;
constexpr int L = 2048;
constexpr int BB = 2;
constexpr int H = 16;
constexpr int DH = 64;
constexpr float NEG_BIG = -1e30f;  // finite -inf stand-in: safe under fast-math

// fp32 x8 -> bf16 x8 (two float4 loads + cvt)
__device__ __forceinline__ bf16x8 cvt8(const float* __restrict__ p) {
  float4 a = *(const float4*)p;
  float4 b = *(const float4*)(p + 4);
  bf16x8 r;
  r[0] = (__bf16)a.x; r[1] = (__bf16)a.y; r[2] = (__bf16)a.z; r[3] = (__bf16)a.w;
  r[4] = (__bf16)b.x; r[5] = (__bf16)b.y; r[6] = (__bf16)b.z; r[7] = (__bf16)b.w;
  return r;
}

// ---------------------------------------------------------------------------
// Transpose 4 fp32 weight matrices W[K][N] -> canonical bf16 Wt[N][K]
// ---------------------------------------------------------------------------
__global__ void transpose_w(const float* __restrict__ w0, const float* __restrict__ w1,
                            const float* __restrict__ w2, const float* __restrict__ w3,
                            __bf16* __restrict__ out) {
  __shared__ __bf16 tile[32][33];
  int mat = blockIdx.z;
  const float* src = mat == 0 ? w0 : mat == 1 ? w1 : mat == 2 ? w2 : w3;
  __bf16* dst = out + (size_t)mat * D * D;
  int bx = blockIdx.x * 32, by = blockIdx.y * 32;
  int tx = threadIdx.x, ty = threadIdx.y;  // block (32, 8)
#pragma unroll
  for (int i = 0; i < 32; i += 8)
    tile[ty + i][tx] = (__bf16)src[(size_t)(by + ty + i) * D + bx + tx];
  __syncthreads();
#pragma unroll
  for (int i = 0; i < 32; i += 8)
    dst[(size_t)(bx + ty + i) * D + by + tx] = tile[tx][ty + i];
}

// ---------------------------------------------------------------------------
// 128x128-tile bf16 MFMA GEMM:  C[M x 1024] = A[M x 1024] @ Bt^T + bias
// AF32: A is wire-fp32, converted to bf16 during staging; else A is bf16.
// SCATTER: write bf16 C to [B,H,L,dh] (for attention); else write fp32 C
// row-major (final output). 256 thr / 4 waves; each wave one 64x64 quadrant
// as 4x4 MFMA 16x16x32 tiles; BK=32; LDS stride 40 (2-way bank alias, free).
// ---------------------------------------------------------------------------
template <bool SCATTER, bool AF32>
__device__ __forceinline__ void gemm128(const float* __restrict__ Af, const __bf16* __restrict__ Ah,
                                        const __bf16* __restrict__ Bt, const float* __restrict__ bias,
                                        __bf16* __restrict__ Cb, float* __restrict__ Cf) {
  __shared__ __align__(16) __bf16 sA[128 * 40];
  __shared__ __align__(16) __bf16 sB[128 * 40];

  const int t = threadIdx.x;
  const int lane = t & 63;
  const int w = t >> 6;
  const int wm = w >> 1, wn = w & 1;
  const int l15 = lane & 15, quad = lane >> 4;
  const int m0 = blockIdx.y * 128;
  const int n0 = blockIdx.x * 128;

  floatx4 acc[4][4];
#pragma unroll
  for (int i = 0; i < 4; i++)
#pragma unroll
    for (int j = 0; j < 4; j++) acc[i][j] = (floatx4){0.f, 0.f, 0.f, 0.f};

  const int r = t >> 2;            // 0..63
  const int c8 = (t & 3) * 8;      // 0,8,16,24

  for (int kb = 0; kb < 1024; kb += 32) {
    const size_t ia0 = (size_t)(m0 + r) * 1024 + kb + c8;
    const size_t ia1 = (size_t)(m0 + r + 64) * 1024 + kb + c8;
    if (AF32) {
      *(bf16x8*)&sA[r * 40 + c8]        = cvt8(&Af[ia0]);
      *(bf16x8*)&sA[(r + 64) * 40 + c8] = cvt8(&Af[ia1]);
    } else {
      *(uint4*)&sA[r * 40 + c8]        = *(const uint4*)&Ah[ia0];
      *(uint4*)&sA[(r + 64) * 40 + c8] = *(const uint4*)&Ah[ia1];
    }
    *(uint4*)&sB[r * 40 + c8]        = *(const uint4*)&Bt[(size_t)(n0 + r) * 1024 + kb + c8];
    *(uint4*)&sB[(r + 64) * 40 + c8] = *(const uint4*)&Bt[(size_t)(n0 + r + 64) * 1024 + kb + c8];
    __syncthreads();

    bf16x8 af[4], bf_[4];
#pragma unroll
    for (int i = 0; i < 4; i++)
      af[i] = *(const bf16x8*)&sA[(wm * 64 + i * 16 + l15) * 40 + quad * 8];
#pragma unroll
    for (int j = 0; j < 4; j++)
      bf_[j] = *(const bf16x8*)&sB[(wn * 64 + j * 16 + l15) * 40 + quad * 8];
#pragma unroll
    for (int i = 0; i < 4; i++)
#pragma unroll
      for (int j = 0; j < 4; j++)
        acc[i][j] = MFMA16(af[i], bf_[j], acc[i][j]);
    __syncthreads();
  }

  // ---- epilogue: + bias, store ----
  float bvv[4];
#pragma unroll
  for (int j = 0; j < 4; j++) bvv[j] = bias[n0 + wn * 64 + j * 16 + l15];

#pragma unroll
  for (int i = 0; i < 4; i++) {
    const int rowb = m0 + wm * 64 + i * 16 + quad * 4;
#pragma unroll
    for (int j = 0; j < 4; j++) {
      const int col = n0 + wn * 64 + j * 16 + l15;
#pragma unroll
      for (int rr = 0; rr < 4; rr++) {
        const float val = acc[i][j][rr] + bvv[j];
        const int row = rowb + rr;
        if (SCATTER) {
          // row = b*2048 + l ; col = h*64 + d  ->  [((b*16+h)*2048+l)*64+d]
          const int b = row >> 11, l = row & 2047;
          const int h = col >> 6, d = col & 63;
          Cb[((size_t)(b * 16 + h) * 2048 + l) * 64 + d] = (__bf16)val;
        } else {
          Cf[(size_t)row * 1024 + col] = val;
        }
      }
    }
  }
}

__global__ __launch_bounds__(256) void gemm_qkv(const float* __restrict__ xq, const float* __restrict__ xk,
                                                const float* __restrict__ xv, const __bf16* __restrict__ wt,
                                                const float* __restrict__ bq, const float* __restrict__ bk,
                                                const float* __restrict__ bv, __bf16* __restrict__ qkv) {
  const int z = blockIdx.z;
  const float* A = z == 0 ? xq : z == 1 ? xk : xv;
  const float* bias = z == 0 ? bq : z == 1 ? bk : bv;
  const __bf16* Bt = wt + (size_t)z * D * D;
  __bf16* C = qkv + (size_t)z * BB * L * D;
  gemm128<true, true>(A, nullptr, Bt, bias, C, nullptr);
}

__global__ __launch_bounds__(256) void gemm_o(const __bf16* __restrict__ ctx, const __bf16* __restrict__ wto,
                                              const float* __restrict__ bo, float* __restrict__ out) {
  gemm128<false, false>(nullptr, ctx, wto, bo, nullptr, out);
}

// ---------------------------------------------------------------------------
// Flash attention, causal.  q/k/v in [B*H, L, 64] bf16 (canonical).
// ctx out [B, L, 1024] bf16.  Grid: (L/64, B*H). Block 256 = 4 waves.
// ---------------------------------------------------------------------------
__global__ __launch_bounds__(256) void flash_attn(const __bf16* __restrict__ q, const __bf16* __restrict__ k,
                                                  const __bf16* __restrict__ v, __bf16* __restrict__ ctx) {
  __shared__ __align__(16) __bf16 p_lds[4][16 * 72];   // per-wave P tile, stride 72
  __shared__ __align__(16) __bf16 vt_lds[64 * 72];     // V^T tile [d][kpos], stride 72

  const int t = threadIdx.x;
  const int lane = t & 63;
  const int w = t >> 6;
  const int l15 = lane & 15, quad = lane >> 4;
  const int bh = blockIdx.y;
  const int q0 = blockIdx.x * 64;

  const __bf16* qb = q + (size_t)bh * L * DH;
  const __bf16* kb = k + (size_t)bh * L * DH;
  const __bf16* vb = v + (size_t)bh * L * DH;

  const int qrow = q0 + w * 16 + l15;
  bf16x8 aq0 = *(const bf16x8*)&qb[(size_t)qrow * 64 + quad * 8];
  bf16x8 aq1 = *(const bf16x8*)&qb[(size_t)qrow * 64 + 32 + quad * 8];

  floatx4 o[4];
#pragma unroll
  for (int nt = 0; nt < 4; nt++) o[nt] = (floatx4){0.f, 0.f, 0.f, 0.f};
  float m_i[4] = {NEG_BIG, NEG_BIG, NEG_BIG, NEG_BIG};
  float l_i[4] = {0.f, 0.f, 0.f, 0.f};

  const int qg_base = q0 + w * 16 + quad * 4;
  const int ntiles = (q0 >> 6) + 1;

  for (int it = 0; it < ntiles; ++it) {
    const int kt = it * 64;
    __syncthreads();

    // ---- stage V^T tile: V[kt+kpos][d] -> vt_lds[d][kpos] ----
    {
      const int kp = t >> 3;           // 0..31
      const int d8 = (t & 7) * 8;      // 0..56
#pragma unroll
      for (int pass = 0; pass < 2; ++pass) {
        const int kpos = kp + pass * 32;
        bf16x8 vv = *(const bf16x8*)&vb[(size_t)(kt + kpos) * 64 + d8];
#pragma unroll
        for (int e = 0; e < 8; ++e) vt_lds[(d8 + e) * 72 + kpos] = vv[e];
      }
    }

    // ---- S = Q K^T ----
    floatx4 s[4];
#pragma unroll
    for (int jt = 0; jt < 4; jt++) {
      bf16x8 bk0 = *(const bf16x8*)&kb[(size_t)(kt + jt * 16 + l15) * 64 + quad * 8];
      bf16x8 bk1 = *(const bf16x8*)&kb[(size_t)(kt + jt * 16 + l15) * 64 + 32 + quad * 8];
      floatx4 z = (floatx4){0.f, 0.f, 0.f, 0.f};
      z = MFMA16(aq0, bk0, z);
      z = MFMA16(aq1, bk1, z);
      s[jt] = z;
    }

    // ---- scale + causal mask (C layout: row = quad*4+rr, col = jt*16+l15) ----
#pragma unroll
    for (int jt = 0; jt < 4; jt++) {
      const int kg = kt + jt * 16 + l15;
#pragma unroll
      for (int rr = 0; rr < 4; rr++) {
        const float sv = s[jt][rr] * 0.125f;
        s[jt][rr] = (kg <= qg_base + rr) ? sv : NEG_BIG;
      }
    }

    // ---- online softmax (rows live in one 16-lane quad) ----
#pragma unroll
    for (int rr = 0; rr < 4; rr++) {
      float mx = fmaxf(fmaxf(s[0][rr], s[1][rr]), fmaxf(s[2][rr], s[3][rr]));
      mx = fmaxf(mx, __shfl_xor(mx, 1));
      mx = fmaxf(mx, __shfl_xor(mx, 2));
      mx = fmaxf(mx, __shfl_xor(mx, 4));
      mx = fmaxf(mx, __shfl_xor(mx, 8));
      const float mnew = fmaxf(m_i[rr], mx);
      const float alpha = __expf(m_i[rr] - mnew);
      float psum = 0.f;
#pragma unroll
      for (int jt = 0; jt < 4; jt++) {
        const float p = __expf(s[jt][rr] - mnew);
        s[jt][rr] = p;
        psum += p;
      }
      psum += __shfl_xor(psum, 1);
      psum += __shfl_xor(psum, 2);
      psum += __shfl_xor(psum, 4);
      psum += __shfl_xor(psum, 8);
      l_i[rr] = alpha * l_i[rr] + psum;
      m_i[rr] = mnew;
#pragma unroll
      for (int nt = 0; nt < 4; nt++) o[nt][rr] *= alpha;
    }

    // ---- P (C layout) -> LDS, per-wave region ----
#pragma unroll
    for (int jt = 0; jt < 4; jt++)
#pragma unroll
      for (int rr = 0; rr < 4; rr++)
        p_lds[w][(quad * 4 + rr) * 72 + jt * 16 + l15] = (__bf16)s[jt][rr];

    __syncthreads();

    // ---- O += P V ----
    bf16x8 pf0 = *(const bf16x8*)&p_lds[w][l15 * 72 + quad * 8];
    bf16x8 pf1 = *(const bf16x8*)&p_lds[w][l15 * 72 + 32 + quad * 8];
#pragma unroll
    for (int nt = 0; nt < 4; nt++) {
      bf16x8 v0 = *(const bf16x8*)&vt_lds[(nt * 16 + l15) * 72 + quad * 8];
      bf16x8 v1 = *(const bf16x8*)&vt_lds[(nt * 16 + l15) * 72 + 32 + quad * 8];
      o[nt] = MFMA16(pf0, v0, o[nt]);
      o[nt] = MFMA16(pf1, v1, o[nt]);
    }
  }

  // ---- normalize and write ctx [B, L, H*64] ----
  const int b = bh >> 4, h = bh & 15;
#pragma unroll
  for (int rr = 0; rr < 4; rr++) {
    const float inv = 1.f / l_i[rr];
    const int row = q0 + w * 16 + quad * 4 + rr;
#pragma unroll
    for (int nt = 0; nt < 4; nt++) {
      const int col = h * 64 + nt * 16 + l15;
      ctx[((size_t)b * L + row) * 1024 + col] = (__bf16)(o[nt][rr] * inv);
    }
  }
}

// ---------------------------------------------------------------------------
extern "C" void kernel_launch(void* const* d_in, const int* in_sizes, int n_in,
                              void* d_out, int out_size, void* d_ws, size_t ws_size,
                              hipStream_t stream) {
  const float* x_q = (const float*)d_in[0];
  const float* x_k = (const float*)d_in[1];
  const float* x_v = (const float*)d_in[2];
  const float* Wq  = (const float*)d_in[3];
  const float* bq  = (const float*)d_in[4];
  const float* Wk  = (const float*)d_in[5];
  const float* bk  = (const float*)d_in[6];
  const float* Wv  = (const float*)d_in[7];
  const float* bv  = (const float*)d_in[8];
  const float* Wo  = (const float*)d_in[9];
  const float* bo  = (const float*)d_in[10];

  char* ws = (char*)d_ws;
  __bf16* wt  = (__bf16*)ws;                          // 4 x 1024x1024 bf16 (8 MB)
  __bf16* qkv = (__bf16*)(ws + ((size_t)8 << 20));    // 3 x [B,H,L,64]     (24 MB)
  __bf16* ctx = (__bf16*)(ws + ((size_t)32 << 20));   // [B,L,1024]         (8 MB)
  __bf16* qp = qkv;
  __bf16* kp = qkv + (size_t)BB * L * D;
  __bf16* vp = qkv + (size_t)2 * BB * L * D;

  transpose_w<<<dim3(32, 32, 4), dim3(32, 8), 0, stream>>>(Wq, Wk, Wv, Wo, wt);
  gemm_qkv<<<dim3(8, 32, 3), 256, 0, stream>>>(x_q, x_k, x_v, wt, bq, bk, bv, qkv);
  flash_attn<<<dim3(L / 64, BB * H), 256, 0, stream>>>(qp, kp, vp, ctx);
  gemm_o<<<dim3(8, 32), 256, 0, stream>>>(ctx, wt + (size_t)3 * D * D, bo, (float*)d_out);
}